// Round 1
// baseline (1026.380 us; speedup 1.0000x reference)
//
#include <hip/hip_runtime.h>

// GIN_MLP: 2x GIN conv (N=100000, E=1.6M, H=128) + per-batch context MLP (B=4096).
// Device-built dst-CSR (rank-based atomic-free scatter, 8-aligned padded rows).
// R12: conv split into agg (feature-QUARTER gather, XCD-affinity via blockIdx%8
// -> quarter = (bid%8)>>1) + gemm (finalize + 128x128 GEMM). Theory: conv was
// miss-queue x latency bound; per-XCD compulsory footprint 51MB -> 12.8MB
// should lift L2 hit rate ~50% -> ~85% and gather throughput ~1.4-1.6x.
// agg output aliases x2 workspace (per-block read-before-write, barrier-sep).

#define CONV_NPB 32
#define FIN_EPB 8

// init: weight transposes + cnt zeroing (grid covers max(N, 90112))
__global__ void init_kernel(const float* __restrict__ W1, const float* __restrict__ W2,
                            const float* __restrict__ Wc1, const float* __restrict__ Wc2,
                            float* __restrict__ Wt1, float* __restrict__ Wt2,
                            float* __restrict__ Wc1t, float* __restrict__ Wc2t,
                            int* __restrict__ cnt, int n) {
  int i = blockIdx.x * blockDim.x + threadIdx.x;
  if (i < n) cnt[i] = 0;
  if (i < 16384) {
    int f = i >> 7, k = i & 127;
    Wt1[k * 128 + f] = W1[i];
  } else if (i < 32768) {
    int j = i - 16384; int f = j >> 7, k = j & 127;
    Wt2[k * 128 + f] = W2[j];
  } else if (i < 81920) {
    int j = i - 32768; int f = j / 384, k = j % 384;
    Wc1t[k * 128 + f] = Wc1[j];
  } else if (i < 90112) {
    int j = i - 81920; int f = j >> 7, k = j & 127;
    Wc2t[k * 64 + f] = Wc2[j];
  }
}

// per-dst degree + per-edge arrival rank; 4 edges/thread
__global__ void hist_kernel(const int* __restrict__ dst, int* __restrict__ cnt,
                            int* __restrict__ rank, int E) {
  int e = (blockIdx.x * blockDim.x + threadIdx.x) * 4;
  if (e + 3 < E) {
    const int4 d = *(const int4*)&dst[e];
    int4 r;
    r.x = atomicAdd(&cnt[d.x], 1);
    r.y = atomicAdd(&cnt[d.y], 1);
    r.z = atomicAdd(&cnt[d.z], 1);
    r.w = atomicAdd(&cnt[d.w], 1);
    *(int4*)&rank[e] = r;
  } else {
    for (; e < E; ++e) rank[e] = atomicAdd(&cnt[dst[e]], 1);
  }
}

// per-2048-chunk exclusive scan of PADDED counts (ceil(cnt/8)*8); bsum[b] = chunk total
__global__ void scan1_kernel(const int* __restrict__ cnt, int* __restrict__ prow,
                             int* __restrict__ bsum, int n) {
  __shared__ int smem[256];
  const int t = threadIdx.x;
  const int base = blockIdx.x * 2048 + t * 8;
  int v[8];
  int s = 0;
#pragma unroll
  for (int j = 0; j < 8; ++j) {
    int idx = base + j;
    v[j] = (idx < n) ? ((cnt[idx] + 7) & ~7) : 0;
    s += v[j];
  }
  smem[t] = s;
  __syncthreads();
  for (int off = 1; off < 256; off <<= 1) {
    int add = (t >= off) ? smem[t - off] : 0;
    __syncthreads();
    smem[t] += add;
    __syncthreads();
  }
  int run = smem[t] - s;
  if (t == 255) bsum[blockIdx.x] = smem[255];
#pragma unroll
  for (int j = 0; j < 8; ++j) {
    int idx = base + j;
    if (idx < n) prow[idx] = run;
    run += v[j];
  }
}

// 64-lane shuffle scan (nchunk=49 fits); appends grand total at bsum[nb]
__global__ void scan2_kernel(int* __restrict__ bsum, int nb) {
  const int t = threadIdx.x;
  if (nb <= 64) {
    const int orig = (t < nb) ? bsum[t] : 0;
    int v = orig;
#pragma unroll
    for (int off = 1; off < 64; off <<= 1) {
      int u = __shfl_up(v, off);
      if (t >= off) v += u;
    }
    if (t == nb - 1) bsum[nb] = v;
    if (t < nb) bsum[t] = v - orig;
  } else if (t == 0) {
    int run = 0;
    for (int i = 0; i < nb; ++i) { int v = bsum[i]; bsum[i] = run; run += v; }
    bsum[nb] = run;
  }
}

// atomic-free scatter into padded CSR, 4 edges/thread; threads i<n also zero
// their node's pad slots (real + pad slots exactly partition the padded CSR)
__global__ void scatter_kernel(const int* __restrict__ src, const int* __restrict__ dst,
                               const float* __restrict__ w, const int* __restrict__ prow,
                               const int* __restrict__ bsum, const int* __restrict__ rank,
                               const int* __restrict__ cnt,
                               int2* __restrict__ epack, int E, int n) {
  const int i = blockIdx.x * blockDim.x + threadIdx.x;
  int e = i * 4;
  if (e + 3 < E) {
    const int4 d = *(const int4*)&dst[e];
    const int4 s = *(const int4*)&src[e];
    const float4 wv = *(const float4*)&w[e];
    const int4 r = *(const int4*)&rank[e];
    epack[prow[d.x] + bsum[d.x >> 11] + r.x] = make_int2(s.x, __float_as_int(wv.x));
    epack[prow[d.y] + bsum[d.y >> 11] + r.y] = make_int2(s.y, __float_as_int(wv.y));
    epack[prow[d.z] + bsum[d.z >> 11] + r.z] = make_int2(s.z, __float_as_int(wv.z));
    epack[prow[d.w] + bsum[d.w >> 11] + r.w] = make_int2(s.w, __float_as_int(wv.w));
  } else {
    for (; e < E; ++e) {
      const int d = dst[e];
      epack[prow[d] + bsum[d >> 11] + rank[e]] = make_int2(src[e], __float_as_int(w[e]));
    }
  }
  if (i < n) {
    const int c = cnt[i];
    const int start = prow[i] + bsum[i >> 11] + c;
    const int pc = ((c + 7) & ~7) - c;
    for (int j = 0; j < pc; ++j) epack[start + j] = make_int2(0, 0);
  }
}

// R12 agg: raw message sums, feature-QUARTER per block.
// Grid = 8 * ceil(NB/2); bid%8 selects XCD (empirical round-robin); quarter
// q = (bid%8)>>1 so each quarter's gather footprint (12.8 MB) is pinned to one
// XCD pair. Node-block nb = (bid>>3)*2 + (bid&1).
// Laneset (32 lanes) walks an 8-aligned edge chunk; per 8-edge batch each lane
// covers 2 edges (ksl = lane>>3 -> edges 2k,2k+1) x one f4 group (lane&7):
// 1 int4 descriptor + 2 float4 gathers (one 128B line per edge). Register acc
// flushes to LDS (xm[r*32 + comp*8 + fg]) at row transitions only.
__launch_bounds__(256, 8)
__global__ void agg_kernel(const float* __restrict__ xin, float* __restrict__ aggout,
                           const int* __restrict__ prow, const int* __restrict__ bsum,
                           const int2* __restrict__ epack,
                           int n, int nchunk, int NB) {
  __shared__ float xm[CONV_NPB * 32];
  __shared__ int rp_s[CONV_NPB + 1];
  const int t = threadIdx.x;
  const int bid = blockIdx.x;
  const int x8 = bid & 7;
  const int q = x8 >> 1;
  const int nb0 = ((bid >> 3) << 1) + (x8 & 1);
  if (nb0 >= NB) return;
  const int nb = nb0 * CONV_NPB;

  *(float4*)&xm[t * 4] = make_float4(0.f, 0.f, 0.f, 0.f);
  if (t <= CONV_NPB) {
    const int node = nb + t;
    rp_s[t] = (node >= n) ? bsum[nchunk] : (prow[node] + bsum[node >> 11]);
  }
  __syncthreads();

  // ---- stage 1: quarter gather ----
  {
    const int L = t >> 5;
    const int lane = t & 31;
    const int fg = lane & 7;
    const int ksl = lane >> 3;                  // 0..3 -> edge pair (2k, 2k+1)
    const int f0 = q * 32 + fg * 4;
    const int e0 = rp_s[0], eT = rp_s[CONV_NPB];
    const int nbat = (eT - e0) >> 3;            // edges per laneset (=batches)
    const int chunk = (((nbat + 7) >> 3)) << 3; // rounded to 8 edges
    const int jb = e0 + L * chunk;
    const int je = min(jb + chunk, eT);
    if (jb < je) {
      const int4* ep4 = (const int4*)epack;
      int r = 0;
      while (rp_s[r + 1] <= jb) ++r;
      float4 acc = make_float4(0.f, 0.f, 0.f, 0.f);
      for (int j = jb; j < je; j += 8) {
        if (rp_s[r + 1] <= j) {
          float* bp = &xm[r * 32 + fg];
          atomicAdd(bp + 0,  acc.x);
          atomicAdd(bp + 8,  acc.y);
          atomicAdd(bp + 16, acc.z);
          atomicAdd(bp + 24, acc.w);
          acc = make_float4(0.f, 0.f, 0.f, 0.f);
          do { ++r; } while (rp_s[r + 1] <= j);
        }
        const int h = j >> 1;                   // int2 idx -> int4 idx
        const int4 d = ep4[h + ksl];            // (src_a, w_a, src_b, w_b)
        const float4 a0 = *(const float4*)&xin[(size_t)d.x * 128 + f0];
        const float4 a1 = *(const float4*)&xin[(size_t)d.z * 128 + f0];
        const float w0 = __int_as_float(d.y), w1 = __int_as_float(d.w);
        acc.x += w0 * a0.x + w1 * a1.x;
        acc.y += w0 * a0.y + w1 * a1.y;
        acc.z += w0 * a0.z + w1 * a1.z;
        acc.w += w0 * a0.w + w1 * a1.w;
      }
      float* bp = &xm[r * 32 + fg];
      atomicAdd(bp + 0,  acc.x);
      atomicAdd(bp + 8,  acc.y);
      atomicAdd(bp + 16, acc.z);
      atomicAdd(bp + 24, acc.w);
    }
  }
  __syncthreads();

  // ---- stage 2: de-permute + write quarter slice (coalesced 128B/row) ----
#pragma unroll
  for (int k = 0; k < 4; ++k) {
    const int task = t + k * 256;               // 1024 = 32 rows x 32 feats
    const int r = task >> 5;
    const int f = task & 31;
    const int node = nb + r;
    if (node < n)
      aggout[(size_t)node * 128 + q * 32 + f] = xm[r * 32 + (f & 3) * 8 + (f >> 2)];
  }
}

// R12 gemm: finalize (1+eps)*x + agg/deg into LDS, then 128x128 GEMM.
// NOTE: agg/xout may alias (conv2 reuses the x2 buffer): per block, all agg
// reads precede all xout writes (barrier-separated) and blocks touch disjoint
// rows -> safe; agg/xout deliberately NOT restrict.
__launch_bounds__(256, 6)
__global__ void gemm_kernel(const float* __restrict__ xin, const float* agg,
                            float* xout, const int* __restrict__ cnt,
                            const float* __restrict__ Wt, const float* __restrict__ bias,
                            const float* __restrict__ eps, int epsidx, int dorelu,
                            int zerorow0, int n) {
  __shared__ float xm[CONV_NPB * 128];
  const int t = threadIdx.x;
  const int nb = blockIdx.x * CONV_NPB;
  const float epsv = 1.0f + eps[epsidx];

  // ---- stage A: v = (1+eps)*x + agg/deg ----
#pragma unroll
  for (int kq = 0; kq < 4; ++kq) {
    const int task = t + kq * 256;
    const int r = task >> 5;
    const int fg = task & 31;
    const int f0 = fg * 4;
    const int node = nb + r;
    float4 v = make_float4(0.f, 0.f, 0.f, 0.f);
    if (node < n) {
      const int d = cnt[node];
      const float rdeg = 1.0f / (float)(d > 1 ? d : 1);
      const float4 xv = *(const float4*)&xin[(size_t)node * 128 + f0];
      const float4 av = *(const float4*)&agg[(size_t)node * 128 + f0];
      v.x = epsv * xv.x + av.x * rdeg;
      v.y = epsv * xv.y + av.y * rdeg;
      v.z = epsv * xv.z + av.z * rdeg;
      v.w = epsv * xv.w + av.w * rdeg;
    }
    *(float4*)&xm[r * 128 + f0] = v;
  }
  __syncthreads();

  // ---- stage B: GEMM, thread tile = 4 rows x 4 features ----
  {
    const int fg = t & 31;
    const int rg = t >> 5;
    const int f0 = fg * 4;
    const int r0 = rg * 4;
    float4 acc[4];
#pragma unroll
    for (int r = 0; r < 4; ++r) acc[r] = make_float4(0.f, 0.f, 0.f, 0.f);
    for (int k = 0; k < 128; k += 4) {
      const float4 w0 = *(const float4*)&Wt[(k + 0) * 128 + f0];
      const float4 w1 = *(const float4*)&Wt[(k + 1) * 128 + f0];
      const float4 w2 = *(const float4*)&Wt[(k + 2) * 128 + f0];
      const float4 w3 = *(const float4*)&Wt[(k + 3) * 128 + f0];
#pragma unroll
      for (int r = 0; r < 4; ++r) {
        const float4 xv = *(const float4*)&xm[(r0 + r) * 128 + k];
        acc[r].x += xv.x * w0.x + xv.y * w1.x + xv.z * w2.x + xv.w * w3.x;
        acc[r].y += xv.x * w0.y + xv.y * w1.y + xv.z * w2.y + xv.w * w3.y;
        acc[r].z += xv.x * w0.z + xv.y * w1.z + xv.z * w2.z + xv.w * w3.z;
        acc[r].w += xv.x * w0.w + xv.y * w1.w + xv.z * w2.w + xv.w * w3.w;
      }
    }
    const float4 bv = *(const float4*)&bias[f0];
#pragma unroll
    for (int r = 0; r < 4; ++r) {
      const int node = nb + r0 + r;
      if (node < n) {
        float4 v;
        v.x = acc[r].x + bv.x;
        v.y = acc[r].y + bv.y;
        v.z = acc[r].z + bv.z;
        v.w = acc[r].w + bv.w;
        if (dorelu) {
          v.x = fmaxf(v.x, 0.f); v.y = fmaxf(v.y, 0.f);
          v.z = fmaxf(v.z, 0.f); v.w = fmaxf(v.w, 0.f);
        }
        if (zerorow0 && node == 0) { v.x = 0.f; v.y = 0.f; v.z = 0.f; v.w = 0.f; }
        *(float4*)&xout[(size_t)node * 128 + f0] = v;
      }
    }
  }
}

// Final MLP (R10, proven): 8 elems per 256-thread block (512 blocks).
__launch_bounds__(256, 4)
__global__ void final_kernel(const float* __restrict__ x2, const int* __restrict__ indices,
                             const float* __restrict__ Wc1t, const float* __restrict__ bc1,
                             const float* __restrict__ Wc2t, const float* __restrict__ bc2,
                             const float* __restrict__ Wc3, const float* __restrict__ bc3,
                             float* __restrict__ out) {
  __shared__ float ysm[FIN_EPB * 384];
  __shared__ float h1s[FIN_EPB * 128];
  __shared__ float h2s[FIN_EPB * 64];
  __shared__ int ind_s[FIN_EPB * 23];
  __shared__ float ccs[FIN_EPB];
  const int t = threadIdx.x;
  const int b0 = blockIdx.x * FIN_EPB;

  if (t < FIN_EPB * 23) ind_s[t] = indices[(size_t)b0 * 23 + t];
  __syncthreads();
  if (t < FIN_EPB) {
    int cc = 0;
#pragma unroll
    for (int j = 0; j < 20; ++j) cc += (ind_s[t * 23 + 3 + j] > 0) ? 1 : 0;
    ccs[t] = 1.0f / (float)(cc > 0 ? cc : 1);
  }
  __syncthreads();

  // ---- phase A ----
  {
#pragma unroll
    for (int q = 0; q < 2; ++q) {
      const int s = t + q * 256;
      const int e = s >> 6;
      const int half = (s >> 5) & 1;
      const int fg = s & 31;
      const int idx = ind_s[e * 23 + half];
      *(float4*)&ysm[e * 384 + half * 128 + fg * 4] =
          *(const float4*)&x2[(size_t)idx * 128 + fg * 4];
    }
    const int e = t >> 5;
    const int fg = t & 31;
    float4 acc = make_float4(0.f, 0.f, 0.f, 0.f);
#pragma unroll
    for (int j = 0; j < 20; ++j) {
      const int cj = ind_s[e * 23 + 3 + j];
      const float4 a = *(const float4*)&x2[(size_t)cj * 128 + fg * 4];
      acc.x += a.x; acc.y += a.y; acc.z += a.z; acc.w += a.w;
    }
    const float sc = ccs[e];
    acc.x *= sc; acc.y *= sc; acc.z *= sc; acc.w *= sc;
    *(float4*)&ysm[e * 384 + 256 + fg * 4] = acc;
  }
  __syncthreads();

  // ---- phase B: layer 1 (384 -> 128), 4 elems per thread ----
  {
    const int f1 = t & 127;
    const int eh = t >> 7;
    float acc[4];
    const float b = bc1[f1];
#pragma unroll
    for (int i = 0; i < 4; ++i) acc[i] = b;
    for (int k = 0; k < 384; k += 4) {
      const float wv0 = Wc1t[(k + 0) * 128 + f1];
      const float wv1 = Wc1t[(k + 1) * 128 + f1];
      const float wv2 = Wc1t[(k + 2) * 128 + f1];
      const float wv3 = Wc1t[(k + 3) * 128 + f1];
#pragma unroll
      for (int i = 0; i < 4; ++i) {
        const float4 yv = *(const float4*)&ysm[(eh * 4 + i) * 384 + k];
        acc[i] += yv.x * wv0 + yv.y * wv1 + yv.z * wv2 + yv.w * wv3;
      }
    }
#pragma unroll
    for (int i = 0; i < 4; ++i)
      h1s[(eh * 4 + i) * 128 + f1] = fmaxf(acc[i], 0.f);
  }
  __syncthreads();

  // ---- phase C: layer 2 (128 -> 64), 2 elems per thread ----
  {
    const int f2 = t & 63;
    const int eg = t >> 6;
    float acc[2];
    const float b = bc2[f2];
#pragma unroll
    for (int i = 0; i < 2; ++i) acc[i] = b;
    for (int k = 0; k < 128; k += 4) {
      const float wv0 = Wc2t[(k + 0) * 64 + f2];
      const float wv1 = Wc2t[(k + 1) * 64 + f2];
      const float wv2 = Wc2t[(k + 2) * 64 + f2];
      const float wv3 = Wc2t[(k + 3) * 64 + f2];
#pragma unroll
      for (int i = 0; i < 2; ++i) {
        const float4 hv = *(const float4*)&h1s[(eg * 2 + i) * 128 + k];
        acc[i] += hv.x * wv0 + hv.y * wv1 + hv.z * wv2 + hv.w * wv3;
      }
    }
#pragma unroll
    for (int i = 0; i < 2; ++i)
      h2s[(eg * 2 + i) * 64 + f2] = fmaxf(acc[i], 0.f);
  }
  __syncthreads();

  // ---- phase D: layer 3 (64 -> 1), 32 lanes per element ----
  {
    const int e = t >> 5;
    const int l = t & 31;
    float p = h2s[e * 64 + l] * Wc3[l] + h2s[e * 64 + l + 32] * Wc3[l + 32];
#pragma unroll
    for (int o = 16; o > 0; o >>= 1) p += __shfl_down(p, o, 32);
    if (l == 0) out[b0 + e] = p + bc3[0];
  }
}

extern "C" void kernel_launch(void* const* d_in, const int* in_sizes, int n_in,
                              void* d_out, int out_size, void* d_ws, size_t ws_size,
                              hipStream_t stream) {
  const int* indices = (const int*)d_in[0];
  const int* src = (const int*)d_in[1];
  const int* dst = (const int*)d_in[2];
  const float* w = (const float*)d_in[3];
  const float* ndata = (const float*)d_in[4];
  const float* W1 = (const float*)d_in[5];
  const float* b1 = (const float*)d_in[6];
  const float* W2 = (const float*)d_in[7];
  const float* b2 = (const float*)d_in[8];
  const float* eps = (const float*)d_in[9];
  const float* Wc1 = (const float*)d_in[10];
  const float* bc1 = (const float*)d_in[11];
  const float* Wc2 = (const float*)d_in[12];
  const float* bc2 = (const float*)d_in[13];
  const float* Wc3 = (const float*)d_in[14];
  const float* bc3 = (const float*)d_in[15];
  float* out = (float*)d_out;

  const int E = in_sizes[1];
  const int N = in_sizes[4] / 128;
  const int B = in_sizes[0] / 23;

  char* ws = (char*)d_ws;
  size_t off = 0;
  auto alloc = [&](size_t bytes) -> char* {
    char* p = ws + off;
    off = (off + bytes + 255) & ~(size_t)255;
    return p;
  };
  const size_t Epad = (size_t)E + 8 * (size_t)N;   // worst-case padded edge count
  int* cnt = (int*)alloc((size_t)N * 4);
  int* prow = (int*)alloc((size_t)(N + 1) * 4);
  int* rank = (int*)alloc((size_t)E * 4);
  int* bsum = (int*)alloc(256 * 4);
  int2* epack = (int2*)alloc(Epad * 8);
  float* x1 = (float*)alloc((size_t)N * 128 * 4);
  float* x2 = (float*)alloc((size_t)N * 128 * 4);
  float* Wt1 = (float*)alloc(16384 * 4);
  float* Wt2 = (float*)alloc(16384 * 4);
  float* Wc1t = (float*)alloc(49152 * 4);
  float* Wc2t = (float*)alloc(8192 * 4);

  const int ninit = (N > 90112) ? N : 90112;
  init_kernel<<<(ninit + 255) / 256, 256, 0, stream>>>(W1, W2, Wc1, Wc2, Wt1, Wt2, Wc1t, Wc2t, cnt, N);
  const int Eq = (E + 3) / 4;
  hist_kernel<<<(Eq + 255) / 256, 256, 0, stream>>>(dst, cnt, rank, E);
  const int nchunk = (N + 2047) / 2048;
  scan1_kernel<<<nchunk, 256, 0, stream>>>(cnt, prow, bsum, N);
  scan2_kernel<<<1, 64, 0, stream>>>(bsum, nchunk);
  const int nsc = (Eq > N) ? Eq : N;
  scatter_kernel<<<(nsc + 255) / 256, 256, 0, stream>>>(src, dst, w, prow, bsum, rank, cnt, epack, E, N);

  const int NB = (N + CONV_NPB - 1) / CONV_NPB;
  const int gridA = 8 * ((NB + 1) / 2);

  // conv1: agg (quarter-sliced, XCD-pinned) into x2 scratch, then gemm -> x1
  agg_kernel<<<gridA, 256, 0, stream>>>(ndata, x2, prow, bsum, epack, N, nchunk, NB);
  gemm_kernel<<<NB, 256, 0, stream>>>(ndata, x2, x1, cnt, Wt1, b1, eps, 0, 1, 0, N);
  // conv2: agg from x1 into x2 scratch, then gemm in-place -> x2
  agg_kernel<<<gridA, 256, 0, stream>>>(x1, x2, prow, bsum, epack, N, nchunk, NB);
  gemm_kernel<<<NB, 256, 0, stream>>>(x1, x2, x2, cnt, Wt2, b2, eps, 1, 0, 1, N);

  final_kernel<<<B / FIN_EPB, 256, 0, stream>>>(x2, indices, Wc1t, bc1, Wc2t, bc2, Wc3, bc3, out);
}

// Round 2
// 554.130 us; speedup vs baseline: 1.8522x; 1.8522x over previous
//
#include <hip/hip_runtime.h>

// GIN_MLP: 2x GIN conv (N=100000, E=1.6M, H=128) + per-batch context MLP (B=4096).
// Device-built dst-CSR (rank-based atomic-free scatter, 8-aligned padded rows)
// -> fused aggregate+GEMM (R7 laneset-f4 gather) -> tiled final MLP. All f32.
// R13: R12 post-mortem showed gather is LATENCY-PARALLELISM bound, not LLC-BW
// bound (R12 fetched less but ran 1.8x slower with 2.5x fewer loads in flight).
// So: revert to R11 structure, raise occupancy cap 6->8 blocks/CU (LDS 135KB
// fits; VGPR<=64 for 8 waves/SIMD) + prefetch next-batch edge descriptors
// across the loop backedge (removes one serialized latency per 8-edge batch).

#define CONV_NPB 32
#define FIN_EPB 8

// init: weight transposes + cnt zeroing (grid covers max(N, 90112))
__global__ void init_kernel(const float* __restrict__ W1, const float* __restrict__ W2,
                            const float* __restrict__ Wc1, const float* __restrict__ Wc2,
                            float* __restrict__ Wt1, float* __restrict__ Wt2,
                            float* __restrict__ Wc1t, float* __restrict__ Wc2t,
                            int* __restrict__ cnt, int n) {
  int i = blockIdx.x * blockDim.x + threadIdx.x;
  if (i < n) cnt[i] = 0;
  if (i < 16384) {
    int f = i >> 7, k = i & 127;
    Wt1[k * 128 + f] = W1[i];
  } else if (i < 32768) {
    int j = i - 16384; int f = j >> 7, k = j & 127;
    Wt2[k * 128 + f] = W2[j];
  } else if (i < 81920) {
    int j = i - 32768; int f = j / 384, k = j % 384;
    Wc1t[k * 128 + f] = Wc1[j];
  } else if (i < 90112) {
    int j = i - 81920; int f = j >> 7, k = j & 127;
    Wc2t[k * 64 + f] = Wc2[j];
  }
}

// per-dst degree + per-edge arrival rank; 4 edges/thread
__global__ void hist_kernel(const int* __restrict__ dst, int* __restrict__ cnt,
                            int* __restrict__ rank, int E) {
  int e = (blockIdx.x * blockDim.x + threadIdx.x) * 4;
  if (e + 3 < E) {
    const int4 d = *(const int4*)&dst[e];
    int4 r;
    r.x = atomicAdd(&cnt[d.x], 1);
    r.y = atomicAdd(&cnt[d.y], 1);
    r.z = atomicAdd(&cnt[d.z], 1);
    r.w = atomicAdd(&cnt[d.w], 1);
    *(int4*)&rank[e] = r;
  } else {
    for (; e < E; ++e) rank[e] = atomicAdd(&cnt[dst[e]], 1);
  }
}

// per-2048-chunk exclusive scan of PADDED counts (ceil(cnt/8)*8); bsum[b] = chunk total
__global__ void scan1_kernel(const int* __restrict__ cnt, int* __restrict__ prow,
                             int* __restrict__ bsum, int n) {
  __shared__ int smem[256];
  const int t = threadIdx.x;
  const int base = blockIdx.x * 2048 + t * 8;
  int v[8];
  int s = 0;
#pragma unroll
  for (int j = 0; j < 8; ++j) {
    int idx = base + j;
    v[j] = (idx < n) ? ((cnt[idx] + 7) & ~7) : 0;
    s += v[j];
  }
  smem[t] = s;
  __syncthreads();
  for (int off = 1; off < 256; off <<= 1) {
    int add = (t >= off) ? smem[t - off] : 0;
    __syncthreads();
    smem[t] += add;
    __syncthreads();
  }
  int run = smem[t] - s;
  if (t == 255) bsum[blockIdx.x] = smem[255];
#pragma unroll
  for (int j = 0; j < 8; ++j) {
    int idx = base + j;
    if (idx < n) prow[idx] = run;
    run += v[j];
  }
}

// 64-lane shuffle scan (nchunk=49 fits); appends grand total at bsum[nb]
__global__ void scan2_kernel(int* __restrict__ bsum, int nb) {
  const int t = threadIdx.x;
  if (nb <= 64) {
    const int orig = (t < nb) ? bsum[t] : 0;
    int v = orig;
#pragma unroll
    for (int off = 1; off < 64; off <<= 1) {
      int u = __shfl_up(v, off);
      if (t >= off) v += u;
    }
    if (t == nb - 1) bsum[nb] = v;
    if (t < nb) bsum[t] = v - orig;
  } else if (t == 0) {
    int run = 0;
    for (int i = 0; i < nb; ++i) { int v = bsum[i]; bsum[i] = run; run += v; }
    bsum[nb] = run;
  }
}

// atomic-free scatter into padded CSR, 4 edges/thread; threads i<n also zero
// their node's pad slots (real + pad slots exactly partition the padded CSR)
__global__ void scatter_kernel(const int* __restrict__ src, const int* __restrict__ dst,
                               const float* __restrict__ w, const int* __restrict__ prow,
                               const int* __restrict__ bsum, const int* __restrict__ rank,
                               const int* __restrict__ cnt,
                               int2* __restrict__ epack, int E, int n) {
  const int i = blockIdx.x * blockDim.x + threadIdx.x;
  int e = i * 4;
  if (e + 3 < E) {
    const int4 d = *(const int4*)&dst[e];
    const int4 s = *(const int4*)&src[e];
    const float4 wv = *(const float4*)&w[e];
    const int4 r = *(const int4*)&rank[e];
    epack[prow[d.x] + bsum[d.x >> 11] + r.x] = make_int2(s.x, __float_as_int(wv.x));
    epack[prow[d.y] + bsum[d.y >> 11] + r.y] = make_int2(s.y, __float_as_int(wv.y));
    epack[prow[d.z] + bsum[d.z >> 11] + r.z] = make_int2(s.z, __float_as_int(wv.z));
    epack[prow[d.w] + bsum[d.w >> 11] + r.w] = make_int2(s.w, __float_as_int(wv.w));
  } else {
    for (; e < E; ++e) {
      const int d = dst[e];
      epack[prow[d] + bsum[d >> 11] + rank[e]] = make_int2(src[e], __float_as_int(w[e]));
    }
  }
  if (i < n) {
    const int c = cnt[i];
    const int start = prow[i] + bsum[i >> 11] + c;
    const int pc = ((c + 7) & ~7) - c;
    for (int j = 0; j < pc; ++j) epack[start + j] = make_int2(0, 0);
  }
}

// Stage 1 (R13): block's 32 rows = contiguous 8-aligned padded edge range,
// split into 8 laneset chunks. Per 8-edge batch: 8 independent float4 gathers
// (issued from PREFETCHED descriptors) + prefetch of next batch's 4 int4
// descriptors + 32 FMA. Register acc flushes to LDS (permuted, bank=lane)
// only at row transitions. Occupancy cap 8 blocks/CU (was 6).
// Stage 2: de-permute + (1+eps)x + agg/deg. Stage 3: GEMM.
__launch_bounds__(256, 8)
__global__ void conv_kernel(const float* __restrict__ xin, float* __restrict__ xout,
                            const int* __restrict__ prow, const int* __restrict__ bsum,
                            const int* __restrict__ cnt,
                            const int2* __restrict__ epack,
                            const float* __restrict__ Wt,
                            const float* __restrict__ bias, const float* __restrict__ eps,
                            int epsidx, int dorelu, int zerorow0, int n, int nchunk) {
  __shared__ float xm[CONV_NPB * 128];
  __shared__ int rp_s[CONV_NPB + 1];
  const int t = threadIdx.x;
  const int nb = blockIdx.x * CONV_NPB;
  const float epsv = 1.0f + eps[epsidx];

#pragma unroll
  for (int i = 0; i < 4; ++i)
    *(float4*)&xm[(t + i * 256) * 4] = make_float4(0.f, 0.f, 0.f, 0.f);
  if (t <= CONV_NPB) {
    const int node = nb + t;
    rp_s[t] = (node >= n) ? bsum[nchunk] : (prow[node] + bsum[node >> 11]);
  }
  __syncthreads();

  // ---- stage 1: padded 8-batch laneset-f4 gather with descriptor prefetch ----
  {
    const int L = t >> 5;
    const int lane = t & 31;
    const int f0 = lane * 4;
    const int e0 = rp_s[0], eT = rp_s[CONV_NPB];
    const int nbat = (eT - e0) >> 3;
    const int chunk = (((nbat + 7) >> 3)) << 3;
    const int jb = e0 + L * chunk;
    const int je = min(jb + chunk, eT);
    if (jb < je) {
      const int4* ep4 = (const int4*)epack;
      int r = 0;
      while (rp_s[r + 1] <= jb) ++r;
      float4 acc = make_float4(0.f, 0.f, 0.f, 0.f);
      // preload first batch's descriptors
      int h = jb >> 1;
      int4 q0 = ep4[h + 0];
      int4 q1 = ep4[h + 1];
      int4 q2 = ep4[h + 2];
      int4 q3 = ep4[h + 3];
      for (int j = jb; j < je; j += 8) {
        if (rp_s[r + 1] <= j) {
          float* bp = &xm[r * 128 + lane];
          atomicAdd(bp + 0,  acc.x);
          atomicAdd(bp + 32, acc.y);
          atomicAdd(bp + 64, acc.z);
          atomicAdd(bp + 96, acc.w);
          acc = make_float4(0.f, 0.f, 0.f, 0.f);
          do { ++r; } while (rp_s[r + 1] <= j);
        }
        // issue the 8 gathers for THIS batch (addresses from q, already resident)
        const float4 a0 = *(const float4*)&xin[(size_t)q0.x * 128 + f0];
        const float4 a1 = *(const float4*)&xin[(size_t)q0.z * 128 + f0];
        const float4 a2 = *(const float4*)&xin[(size_t)q1.x * 128 + f0];
        const float4 a3 = *(const float4*)&xin[(size_t)q1.z * 128 + f0];
        const float4 a4 = *(const float4*)&xin[(size_t)q2.x * 128 + f0];
        const float4 a5 = *(const float4*)&xin[(size_t)q2.z * 128 + f0];
        const float4 a6 = *(const float4*)&xin[(size_t)q3.x * 128 + f0];
        const float4 a7 = *(const float4*)&xin[(size_t)q3.z * 128 + f0];
        const float w0 = __int_as_float(q0.y), w1 = __int_as_float(q0.w);
        const float w2 = __int_as_float(q1.y), w3 = __int_as_float(q1.w);
        const float w4 = __int_as_float(q2.y), w5 = __int_as_float(q2.w);
        const float w6 = __int_as_float(q3.y), w7 = __int_as_float(q3.w);
        // prefetch NEXT batch's descriptors (clamped address; laneset-uniform,
        // branch-free; overlaps with the gathers above)
        const int jn = (j + 8 < je) ? (j + 8) : j;
        const int hn = jn >> 1;
        q0 = ep4[hn + 0];
        q1 = ep4[hn + 1];
        q2 = ep4[hn + 2];
        q3 = ep4[hn + 3];
        acc.x += w0 * a0.x + w1 * a1.x + w2 * a2.x + w3 * a3.x
               + w4 * a4.x + w5 * a5.x + w6 * a6.x + w7 * a7.x;
        acc.y += w0 * a0.y + w1 * a1.y + w2 * a2.y + w3 * a3.y
               + w4 * a4.y + w5 * a5.y + w6 * a6.y + w7 * a7.y;
        acc.z += w0 * a0.z + w1 * a1.z + w2 * a2.z + w3 * a3.z
               + w4 * a4.z + w5 * a5.z + w6 * a6.z + w7 * a7.z;
        acc.w += w0 * a0.w + w1 * a1.w + w2 * a2.w + w3 * a3.w
               + w4 * a4.w + w5 * a5.w + w6 * a6.w + w7 * a7.w;
      }
      float* bp = &xm[r * 128 + lane];
      atomicAdd(bp + 0,  acc.x);
      atomicAdd(bp + 32, acc.y);
      atomicAdd(bp + 64, acc.z);
      atomicAdd(bp + 96, acc.w);
    }
  }
  __syncthreads();

  // ---- stage 2: de-permute + finalize (1+eps)*x + agg/deg ----
  {
    float4 m[4];
#pragma unroll
    for (int q = 0; q < 4; ++q) {
      const int task = t + q * 256;
      const int r = task >> 5;
      const int fg = task & 31;
      m[q].x = xm[r * 128 + fg];
      m[q].y = xm[r * 128 + 32 + fg];
      m[q].z = xm[r * 128 + 64 + fg];
      m[q].w = xm[r * 128 + 96 + fg];
    }
    __syncthreads();
#pragma unroll
    for (int q = 0; q < 4; ++q) {
      const int task = t + q * 256;
      const int r = task >> 5;
      const int fg = task & 31;
      const int f0 = fg * 4;
      const int node = nb + r;
      float4 v = make_float4(0.f, 0.f, 0.f, 0.f);
      if (node < n) {
        const int d = cnt[node];
        const float rdeg = 1.0f / (float)(d > 1 ? d : 1);
        const float4 xv = *(const float4*)&xin[(size_t)node * 128 + f0];
        v.x = epsv * xv.x + m[q].x * rdeg;
        v.y = epsv * xv.y + m[q].y * rdeg;
        v.z = epsv * xv.z + m[q].z * rdeg;
        v.w = epsv * xv.w + m[q].w * rdeg;
      }
      *(float4*)&xm[r * 128 + f0] = v;
    }
  }
  __syncthreads();

  // ---- stage 3: GEMM, thread tile = 4 rows x 4 features ----
  {
    const int fg = t & 31;
    const int rg = t >> 5;
    const int f0 = fg * 4;
    const int r0 = rg * 4;
    float4 acc[4];
#pragma unroll
    for (int r = 0; r < 4; ++r) acc[r] = make_float4(0.f, 0.f, 0.f, 0.f);
    for (int k = 0; k < 128; k += 4) {
      const float4 w0 = *(const float4*)&Wt[(k + 0) * 128 + f0];
      const float4 w1 = *(const float4*)&Wt[(k + 1) * 128 + f0];
      const float4 w2 = *(const float4*)&Wt[(k + 2) * 128 + f0];
      const float4 w3 = *(const float4*)&Wt[(k + 3) * 128 + f0];
#pragma unroll
      for (int r = 0; r < 4; ++r) {
        const float4 xv = *(const float4*)&xm[(r0 + r) * 128 + k];
        acc[r].x += xv.x * w0.x + xv.y * w1.x + xv.z * w2.x + xv.w * w3.x;
        acc[r].y += xv.x * w0.y + xv.y * w1.y + xv.z * w2.y + xv.w * w3.y;
        acc[r].z += xv.x * w0.z + xv.y * w1.z + xv.z * w2.z + xv.w * w3.z;
        acc[r].w += xv.x * w0.w + xv.y * w1.w + xv.z * w2.w + xv.w * w3.w;
      }
    }
    const float4 bv = *(const float4*)&bias[f0];
#pragma unroll
    for (int r = 0; r < 4; ++r) {
      const int node = nb + r0 + r;
      if (node < n) {
        float4 v;
        v.x = acc[r].x + bv.x;
        v.y = acc[r].y + bv.y;
        v.z = acc[r].z + bv.z;
        v.w = acc[r].w + bv.w;
        if (dorelu) {
          v.x = fmaxf(v.x, 0.f); v.y = fmaxf(v.y, 0.f);
          v.z = fmaxf(v.z, 0.f); v.w = fmaxf(v.w, 0.f);
        }
        if (zerorow0 && node == 0) { v.x = 0.f; v.y = 0.f; v.z = 0.f; v.w = 0.f; }
        *(float4*)&xout[(size_t)node * 128 + f0] = v;
      }
    }
  }
}

// Final MLP (R10, proven): 8 elems per 256-thread block (512 blocks).
__launch_bounds__(256, 4)
__global__ void final_kernel(const float* __restrict__ x2, const int* __restrict__ indices,
                             const float* __restrict__ Wc1t, const float* __restrict__ bc1,
                             const float* __restrict__ Wc2t, const float* __restrict__ bc2,
                             const float* __restrict__ Wc3, const float* __restrict__ bc3,
                             float* __restrict__ out) {
  __shared__ float ysm[FIN_EPB * 384];
  __shared__ float h1s[FIN_EPB * 128];
  __shared__ float h2s[FIN_EPB * 64];
  __shared__ int ind_s[FIN_EPB * 23];
  __shared__ float ccs[FIN_EPB];
  const int t = threadIdx.x;
  const int b0 = blockIdx.x * FIN_EPB;

  if (t < FIN_EPB * 23) ind_s[t] = indices[(size_t)b0 * 23 + t];
  __syncthreads();
  if (t < FIN_EPB) {
    int cc = 0;
#pragma unroll
    for (int j = 0; j < 20; ++j) cc += (ind_s[t * 23 + 3 + j] > 0) ? 1 : 0;
    ccs[t] = 1.0f / (float)(cc > 0 ? cc : 1);
  }
  __syncthreads();

  // ---- phase A ----
  {
#pragma unroll
    for (int q = 0; q < 2; ++q) {
      const int s = t + q * 256;
      const int e = s >> 6;
      const int half = (s >> 5) & 1;
      const int fg = s & 31;
      const int idx = ind_s[e * 23 + half];
      *(float4*)&ysm[e * 384 + half * 128 + fg * 4] =
          *(const float4*)&x2[(size_t)idx * 128 + fg * 4];
    }
    const int e = t >> 5;
    const int fg = t & 31;
    float4 acc = make_float4(0.f, 0.f, 0.f, 0.f);
#pragma unroll
    for (int j = 0; j < 20; ++j) {
      const int cj = ind_s[e * 23 + 3 + j];
      const float4 a = *(const float4*)&x2[(size_t)cj * 128 + fg * 4];
      acc.x += a.x; acc.y += a.y; acc.z += a.z; acc.w += a.w;
    }
    const float sc = ccs[e];
    acc.x *= sc; acc.y *= sc; acc.z *= sc; acc.w *= sc;
    *(float4*)&ysm[e * 384 + 256 + fg * 4] = acc;
  }
  __syncthreads();

  // ---- phase B: layer 1 (384 -> 128), 4 elems per thread ----
  {
    const int f1 = t & 127;
    const int eh = t >> 7;
    float acc[4];
    const float b = bc1[f1];
#pragma unroll
    for (int i = 0; i < 4; ++i) acc[i] = b;
    for (int k = 0; k < 384; k += 4) {
      const float wv0 = Wc1t[(k + 0) * 128 + f1];
      const float wv1 = Wc1t[(k + 1) * 128 + f1];
      const float wv2 = Wc1t[(k + 2) * 128 + f1];
      const float wv3 = Wc1t[(k + 3) * 128 + f1];
#pragma unroll
      for (int i = 0; i < 4; ++i) {
        const float4 yv = *(const float4*)&ysm[(eh * 4 + i) * 384 + k];
        acc[i] += yv.x * wv0 + yv.y * wv1 + yv.z * wv2 + yv.w * wv3;
      }
    }
#pragma unroll
    for (int i = 0; i < 4; ++i)
      h1s[(eh * 4 + i) * 128 + f1] = fmaxf(acc[i], 0.f);
  }
  __syncthreads();

  // ---- phase C: layer 2 (128 -> 64), 2 elems per thread ----
  {
    const int f2 = t & 63;
    const int eg = t >> 6;
    float acc[2];
    const float b = bc2[f2];
#pragma unroll
    for (int i = 0; i < 2; ++i) acc[i] = b;
    for (int k = 0; k < 128; k += 4) {
      const float wv0 = Wc2t[(k + 0) * 64 + f2];
      const float wv1 = Wc2t[(k + 1) * 64 + f2];
      const float wv2 = Wc2t[(k + 2) * 64 + f2];
      const float wv3 = Wc2t[(k + 3) * 64 + f2];
#pragma unroll
      for (int i = 0; i < 2; ++i) {
        const float4 hv = *(const float4*)&h1s[(eg * 2 + i) * 128 + k];
        acc[i] += hv.x * wv0 + hv.y * wv1 + hv.z * wv2 + hv.w * wv3;
      }
    }
#pragma unroll
    for (int i = 0; i < 2; ++i)
      h2s[(eg * 2 + i) * 64 + f2] = fmaxf(acc[i], 0.f);
  }
  __syncthreads();

  // ---- phase D: layer 3 (64 -> 1), 32 lanes per element ----
  {
    const int e = t >> 5;
    const int l = t & 31;
    float p = h2s[e * 64 + l] * Wc3[l] + h2s[e * 64 + l + 32] * Wc3[l + 32];
#pragma unroll
    for (int o = 16; o > 0; o >>= 1) p += __shfl_down(p, o, 32);
    if (l == 0) out[b0 + e] = p + bc3[0];
  }
}

extern "C" void kernel_launch(void* const* d_in, const int* in_sizes, int n_in,
                              void* d_out, int out_size, void* d_ws, size_t ws_size,
                              hipStream_t stream) {
  const int* indices = (const int*)d_in[0];
  const int* src = (const int*)d_in[1];
  const int* dst = (const int*)d_in[2];
  const float* w = (const float*)d_in[3];
  const float* ndata = (const float*)d_in[4];
  const float* W1 = (const float*)d_in[5];
  const float* b1 = (const float*)d_in[6];
  const float* W2 = (const float*)d_in[7];
  const float* b2 = (const float*)d_in[8];
  const float* eps = (const float*)d_in[9];
  const float* Wc1 = (const float*)d_in[10];
  const float* bc1 = (const float*)d_in[11];
  const float* Wc2 = (const float*)d_in[12];
  const float* bc2 = (const float*)d_in[13];
  const float* Wc3 = (const float*)d_in[14];
  const float* bc3 = (const float*)d_in[15];
  float* out = (float*)d_out;

  const int E = in_sizes[1];
  const int N = in_sizes[4] / 128;
  const int B = in_sizes[0] / 23;

  char* ws = (char*)d_ws;
  size_t off = 0;
  auto alloc = [&](size_t bytes) -> char* {
    char* p = ws + off;
    off = (off + bytes + 255) & ~(size_t)255;
    return p;
  };
  const size_t Epad = (size_t)E + 8 * (size_t)N;   // worst-case padded edge count
  int* cnt = (int*)alloc((size_t)N * 4);
  int* prow = (int*)alloc((size_t)(N + 1) * 4);
  int* rank = (int*)alloc((size_t)E * 4);
  int* bsum = (int*)alloc(256 * 4);
  int2* epack = (int2*)alloc(Epad * 8);
  float* x1 = (float*)alloc((size_t)N * 128 * 4);
  float* x2 = (float*)alloc((size_t)N * 128 * 4);
  float* Wt1 = (float*)alloc(16384 * 4);
  float* Wt2 = (float*)alloc(16384 * 4);
  float* Wc1t = (float*)alloc(49152 * 4);
  float* Wc2t = (float*)alloc(8192 * 4);

  const int ninit = (N > 90112) ? N : 90112;
  init_kernel<<<(ninit + 255) / 256, 256, 0, stream>>>(W1, W2, Wc1, Wc2, Wt1, Wt2, Wc1t, Wc2t, cnt, N);
  const int Eq = (E + 3) / 4;
  hist_kernel<<<(Eq + 255) / 256, 256, 0, stream>>>(dst, cnt, rank, E);
  const int nchunk = (N + 2047) / 2048;
  scan1_kernel<<<nchunk, 256, 0, stream>>>(cnt, prow, bsum, N);
  scan2_kernel<<<1, 64, 0, stream>>>(bsum, nchunk);
  const int nsc = (Eq > N) ? Eq : N;
  scatter_kernel<<<(nsc + 255) / 256, 256, 0, stream>>>(src, dst, w, prow, bsum, rank, cnt, epack, E, N);

  const int nconv = (N + CONV_NPB - 1) / CONV_NPB;
  conv_kernel<<<nconv, 256, 0, stream>>>(ndata, x1, prow, bsum, cnt, epack, Wt1, b1, eps, 0, 1, 0, N, nchunk);
  conv_kernel<<<nconv, 256, 0, stream>>>(x1, x2, prow, bsum, cnt, epack, Wt2, b2, eps, 1, 0, 1, N, nchunk);

  final_kernel<<<B / FIN_EPB, 256, 0, stream>>>(x2, indices, Wc1t, bc1, Wc2t, bc2, Wc3, bc3, out);
}

// Round 3
// 513.666 us; speedup vs baseline: 1.9981x; 1.0788x over previous
//
#include <hip/hip_runtime.h>
#include <hip/hip_fp16.h>

// GIN_MLP: 2x GIN conv (N=100000, E=1.6M, H=128) + per-batch context MLP (B=4096).
// Device-built dst-CSR (rank-based atomic-free scatter, 8-aligned padded rows)
// -> fused aggregate+GEMM (R13 laneset gather w/ descriptor prefetch, 8 blk/CU)
// -> tiled final MLP.
// R14: conv gather is a latency x outstanding-line wall (~0.066 lines/cy/CU,
// R12/R13 evidence). M (miss queue) and T (latency) are pinned by HW, so halve
// the LINES: gather rows in fp16 (512B->256B, 4->2 lines/edge). Self term
// (1+eps)x and all GEMMs stay f32; only scattered messages + final's random
// x2 gathers are fp16 (error ~1e-4 at output, an order under current absmax).
// x2 exists only as fp16 (aliases the fp16-ndata buffer; dead after conv1).

#define CONV_NPB 32
#define FIN_EPB 8

struct __align__(8)  h4 { __half2 a, b; };
struct __align__(16) h8 { __half2 a, b, c, d; };

__device__ __forceinline__ float4 h4f(h4 u) {
  return make_float4(__low2float(u.a), __high2float(u.a),
                     __low2float(u.b), __high2float(u.b));
}
__device__ __forceinline__ h4 f4h(float4 v) {
  h4 u; u.a = __floats2half2_rn(v.x, v.y); u.b = __floats2half2_rn(v.z, v.w);
  return u;
}

// init: weight transposes + cnt zeroing + fp16 cast of ndata (8 elems/thread)
__global__ void init_kernel(const float* __restrict__ W1, const float* __restrict__ W2,
                            const float* __restrict__ Wc1, const float* __restrict__ Wc2,
                            const float* __restrict__ ndata, __half* __restrict__ xh0,
                            float* __restrict__ Wt1, float* __restrict__ Wt2,
                            float* __restrict__ Wc1t, float* __restrict__ Wc2t,
                            int* __restrict__ cnt, int n) {
  int i = blockIdx.x * blockDim.x + threadIdx.x;
  if (i < n) cnt[i] = 0;
  const int cbase = i * 8;
  if (cbase < n * 128) {
    const float4 v0 = *(const float4*)&ndata[cbase];
    const float4 v1 = *(const float4*)&ndata[cbase + 4];
    h8 u;
    u.a = __floats2half2_rn(v0.x, v0.y);
    u.b = __floats2half2_rn(v0.z, v0.w);
    u.c = __floats2half2_rn(v1.x, v1.y);
    u.d = __floats2half2_rn(v1.z, v1.w);
    *(h8*)&xh0[cbase] = u;
  }
  if (i < 16384) {
    int f = i >> 7, k = i & 127;
    Wt1[k * 128 + f] = W1[i];
  } else if (i < 32768) {
    int j = i - 16384; int f = j >> 7, k = j & 127;
    Wt2[k * 128 + f] = W2[j];
  } else if (i < 81920) {
    int j = i - 32768; int f = j / 384, k = j % 384;
    Wc1t[k * 128 + f] = Wc1[j];
  } else if (i < 90112) {
    int j = i - 81920; int f = j >> 7, k = j & 127;
    Wc2t[k * 64 + f] = Wc2[j];
  }
}

// per-dst degree + per-edge arrival rank; 4 edges/thread
__global__ void hist_kernel(const int* __restrict__ dst, int* __restrict__ cnt,
                            int* __restrict__ rank, int E) {
  int e = (blockIdx.x * blockDim.x + threadIdx.x) * 4;
  if (e + 3 < E) {
    const int4 d = *(const int4*)&dst[e];
    int4 r;
    r.x = atomicAdd(&cnt[d.x], 1);
    r.y = atomicAdd(&cnt[d.y], 1);
    r.z = atomicAdd(&cnt[d.z], 1);
    r.w = atomicAdd(&cnt[d.w], 1);
    *(int4*)&rank[e] = r;
  } else {
    for (; e < E; ++e) rank[e] = atomicAdd(&cnt[dst[e]], 1);
  }
}

// per-2048-chunk exclusive scan of PADDED counts (ceil(cnt/8)*8); bsum[b] = chunk total
__global__ void scan1_kernel(const int* __restrict__ cnt, int* __restrict__ prow,
                             int* __restrict__ bsum, int n) {
  __shared__ int smem[256];
  const int t = threadIdx.x;
  const int base = blockIdx.x * 2048 + t * 8;
  int v[8];
  int s = 0;
#pragma unroll
  for (int j = 0; j < 8; ++j) {
    int idx = base + j;
    v[j] = (idx < n) ? ((cnt[idx] + 7) & ~7) : 0;
    s += v[j];
  }
  smem[t] = s;
  __syncthreads();
  for (int off = 1; off < 256; off <<= 1) {
    int add = (t >= off) ? smem[t - off] : 0;
    __syncthreads();
    smem[t] += add;
    __syncthreads();
  }
  int run = smem[t] - s;
  if (t == 255) bsum[blockIdx.x] = smem[255];
#pragma unroll
  for (int j = 0; j < 8; ++j) {
    int idx = base + j;
    if (idx < n) prow[idx] = run;
    run += v[j];
  }
}

// 64-lane shuffle scan (nchunk=49 fits); appends grand total at bsum[nb]
__global__ void scan2_kernel(int* __restrict__ bsum, int nb) {
  const int t = threadIdx.x;
  if (nb <= 64) {
    const int orig = (t < nb) ? bsum[t] : 0;
    int v = orig;
#pragma unroll
    for (int off = 1; off < 64; off <<= 1) {
      int u = __shfl_up(v, off);
      if (t >= off) v += u;
    }
    if (t == nb - 1) bsum[nb] = v;
    if (t < nb) bsum[t] = v - orig;
  } else if (t == 0) {
    int run = 0;
    for (int i = 0; i < nb; ++i) { int v = bsum[i]; bsum[i] = run; run += v; }
    bsum[nb] = run;
  }
}

// atomic-free scatter into padded CSR, 4 edges/thread; threads i<n also zero
// their node's pad slots (real + pad slots exactly partition the padded CSR)
__global__ void scatter_kernel(const int* __restrict__ src, const int* __restrict__ dst,
                               const float* __restrict__ w, const int* __restrict__ prow,
                               const int* __restrict__ bsum, const int* __restrict__ rank,
                               const int* __restrict__ cnt,
                               int2* __restrict__ epack, int E, int n) {
  const int i = blockIdx.x * blockDim.x + threadIdx.x;
  int e = i * 4;
  if (e + 3 < E) {
    const int4 d = *(const int4*)&dst[e];
    const int4 s = *(const int4*)&src[e];
    const float4 wv = *(const float4*)&w[e];
    const int4 r = *(const int4*)&rank[e];
    epack[prow[d.x] + bsum[d.x >> 11] + r.x] = make_int2(s.x, __float_as_int(wv.x));
    epack[prow[d.y] + bsum[d.y >> 11] + r.y] = make_int2(s.y, __float_as_int(wv.y));
    epack[prow[d.z] + bsum[d.z >> 11] + r.z] = make_int2(s.z, __float_as_int(wv.z));
    epack[prow[d.w] + bsum[d.w >> 11] + r.w] = make_int2(s.w, __float_as_int(wv.w));
  } else {
    for (; e < E; ++e) {
      const int d = dst[e];
      epack[prow[d] + bsum[d >> 11] + rank[e]] = make_int2(src[e], __float_as_int(w[e]));
    }
  }
  if (i < n) {
    const int c = cnt[i];
    const int start = prow[i] + bsum[i >> 11] + c;
    const int pc = ((c + 7) & ~7) - c;
    for (int j = 0; j < pc; ++j) epack[start + j] = make_int2(0, 0);
  }
}

// Stage 1 (R14): block's 32 rows = contiguous 8-aligned padded edge range,
// split into 8 laneset chunks. Per 8-edge batch: 8 independent 8B fp16-row
// gathers (from PREFETCHED descriptors; 2 cache lines per edge, was 4) +
// prefetch of next batch's 4 int4 descriptors + cvt + 32 FMA. Register acc
// flushes to LDS (permuted, bank=lane) only at row transitions. 8 blocks/CU.
// Stage 2: de-permute + (1+eps)x(f32) + agg/deg. Stage 3: GEMM (f32).
// Epilogue writes fp16 always, f32 only when writef32 (conv1, for conv2 self).
__launch_bounds__(256, 8)
__global__ void conv_kernel(const float* __restrict__ xin, const __half* __restrict__ xinh,
                            float* __restrict__ xout, __half* __restrict__ xouth,
                            const int* __restrict__ prow, const int* __restrict__ bsum,
                            const int* __restrict__ cnt,
                            const int2* __restrict__ epack,
                            const float* __restrict__ Wt,
                            const float* __restrict__ bias, const float* __restrict__ eps,
                            int epsidx, int dorelu, int zerorow0, int writef32,
                            int n, int nchunk) {
  __shared__ float xm[CONV_NPB * 128];
  __shared__ int rp_s[CONV_NPB + 1];
  const int t = threadIdx.x;
  const int nb = blockIdx.x * CONV_NPB;
  const float epsv = 1.0f + eps[epsidx];

#pragma unroll
  for (int i = 0; i < 4; ++i)
    *(float4*)&xm[(t + i * 256) * 4] = make_float4(0.f, 0.f, 0.f, 0.f);
  if (t <= CONV_NPB) {
    const int node = nb + t;
    rp_s[t] = (node >= n) ? bsum[nchunk] : (prow[node] + bsum[node >> 11]);
  }
  __syncthreads();

  // ---- stage 1: padded 8-batch laneset fp16 gather with descriptor prefetch ----
  {
    const int L = t >> 5;
    const int lane = t & 31;
    const int f0 = lane * 4;
    const int e0 = rp_s[0], eT = rp_s[CONV_NPB];
    const int nbat = (eT - e0) >> 3;
    const int chunk = (((nbat + 7) >> 3)) << 3;
    const int jb = e0 + L * chunk;
    const int je = min(jb + chunk, eT);
    if (jb < je) {
      const int4* ep4 = (const int4*)epack;
      int r = 0;
      while (rp_s[r + 1] <= jb) ++r;
      float4 acc = make_float4(0.f, 0.f, 0.f, 0.f);
      // preload first batch's descriptors
      int h = jb >> 1;
      int4 q0 = ep4[h + 0];
      int4 q1 = ep4[h + 1];
      int4 q2 = ep4[h + 2];
      int4 q3 = ep4[h + 3];
      for (int j = jb; j < je; j += 8) {
        if (rp_s[r + 1] <= j) {
          float* bp = &xm[r * 128 + lane];
          atomicAdd(bp + 0,  acc.x);
          atomicAdd(bp + 32, acc.y);
          atomicAdd(bp + 64, acc.z);
          atomicAdd(bp + 96, acc.w);
          acc = make_float4(0.f, 0.f, 0.f, 0.f);
          do { ++r; } while (rp_s[r + 1] <= j);
        }
        // issue the 8 fp16 gathers for THIS batch (addresses already resident)
        const h4 u0 = *(const h4*)&xinh[(size_t)q0.x * 128 + f0];
        const h4 u1 = *(const h4*)&xinh[(size_t)q0.z * 128 + f0];
        const h4 u2 = *(const h4*)&xinh[(size_t)q1.x * 128 + f0];
        const h4 u3 = *(const h4*)&xinh[(size_t)q1.z * 128 + f0];
        const h4 u4 = *(const h4*)&xinh[(size_t)q2.x * 128 + f0];
        const h4 u5 = *(const h4*)&xinh[(size_t)q2.z * 128 + f0];
        const h4 u6 = *(const h4*)&xinh[(size_t)q3.x * 128 + f0];
        const h4 u7 = *(const h4*)&xinh[(size_t)q3.z * 128 + f0];
        const float w0 = __int_as_float(q0.y), w1 = __int_as_float(q0.w);
        const float w2 = __int_as_float(q1.y), w3 = __int_as_float(q1.w);
        const float w4 = __int_as_float(q2.y), w5 = __int_as_float(q2.w);
        const float w6 = __int_as_float(q3.y), w7 = __int_as_float(q3.w);
        // prefetch NEXT batch's descriptors (clamped, branch-free)
        const int jn = (j + 8 < je) ? (j + 8) : j;
        const int hn = jn >> 1;
        q0 = ep4[hn + 0];
        q1 = ep4[hn + 1];
        q2 = ep4[hn + 2];
        q3 = ep4[hn + 3];
        const float4 a0 = h4f(u0), a1 = h4f(u1), a2 = h4f(u2), a3 = h4f(u3);
        const float4 a4 = h4f(u4), a5 = h4f(u5), a6 = h4f(u6), a7 = h4f(u7);
        acc.x += w0 * a0.x + w1 * a1.x + w2 * a2.x + w3 * a3.x
               + w4 * a4.x + w5 * a5.x + w6 * a6.x + w7 * a7.x;
        acc.y += w0 * a0.y + w1 * a1.y + w2 * a2.y + w3 * a3.y
               + w4 * a4.y + w5 * a5.y + w6 * a6.y + w7 * a7.y;
        acc.z += w0 * a0.z + w1 * a1.z + w2 * a2.z + w3 * a3.z
               + w4 * a4.z + w5 * a5.z + w6 * a6.z + w7 * a7.z;
        acc.w += w0 * a0.w + w1 * a1.w + w2 * a2.w + w3 * a3.w
               + w4 * a4.w + w5 * a5.w + w6 * a6.w + w7 * a7.w;
      }
      float* bp = &xm[r * 128 + lane];
      atomicAdd(bp + 0,  acc.x);
      atomicAdd(bp + 32, acc.y);
      atomicAdd(bp + 64, acc.z);
      atomicAdd(bp + 96, acc.w);
    }
  }
  __syncthreads();

  // ---- stage 2: de-permute + finalize (1+eps)*x + agg/deg ----
  {
    float4 m[4];
#pragma unroll
    for (int q = 0; q < 4; ++q) {
      const int task = t + q * 256;
      const int r = task >> 5;
      const int fg = task & 31;
      m[q].x = xm[r * 128 + fg];
      m[q].y = xm[r * 128 + 32 + fg];
      m[q].z = xm[r * 128 + 64 + fg];
      m[q].w = xm[r * 128 + 96 + fg];
    }
    __syncthreads();
#pragma unroll
    for (int q = 0; q < 4; ++q) {
      const int task = t + q * 256;
      const int r = task >> 5;
      const int fg = task & 31;
      const int f0 = fg * 4;
      const int node = nb + r;
      float4 v = make_float4(0.f, 0.f, 0.f, 0.f);
      if (node < n) {
        const int d = cnt[node];
        const float rdeg = 1.0f / (float)(d > 1 ? d : 1);
        const float4 xv = *(const float4*)&xin[(size_t)node * 128 + f0];
        v.x = epsv * xv.x + m[q].x * rdeg;
        v.y = epsv * xv.y + m[q].y * rdeg;
        v.z = epsv * xv.z + m[q].z * rdeg;
        v.w = epsv * xv.w + m[q].w * rdeg;
      }
      *(float4*)&xm[r * 128 + f0] = v;
    }
  }
  __syncthreads();

  // ---- stage 3: GEMM, thread tile = 4 rows x 4 features ----
  {
    const int fg = t & 31;
    const int rg = t >> 5;
    const int f0 = fg * 4;
    const int r0 = rg * 4;
    float4 acc[4];
#pragma unroll
    for (int r = 0; r < 4; ++r) acc[r] = make_float4(0.f, 0.f, 0.f, 0.f);
    for (int k = 0; k < 128; k += 4) {
      const float4 w0 = *(const float4*)&Wt[(k + 0) * 128 + f0];
      const float4 w1 = *(const float4*)&Wt[(k + 1) * 128 + f0];
      const float4 w2 = *(const float4*)&Wt[(k + 2) * 128 + f0];
      const float4 w3 = *(const float4*)&Wt[(k + 3) * 128 + f0];
#pragma unroll
      for (int r = 0; r < 4; ++r) {
        const float4 xv = *(const float4*)&xm[(r0 + r) * 128 + k];
        acc[r].x += xv.x * w0.x + xv.y * w1.x + xv.z * w2.x + xv.w * w3.x;
        acc[r].y += xv.x * w0.y + xv.y * w1.y + xv.z * w2.y + xv.w * w3.y;
        acc[r].z += xv.x * w0.z + xv.y * w1.z + xv.z * w2.z + xv.w * w3.z;
        acc[r].w += xv.x * w0.w + xv.y * w1.w + xv.z * w2.w + xv.w * w3.w;
      }
    }
    const float4 bv = *(const float4*)&bias[f0];
#pragma unroll
    for (int r = 0; r < 4; ++r) {
      const int node = nb + r0 + r;
      if (node < n) {
        float4 v;
        v.x = acc[r].x + bv.x;
        v.y = acc[r].y + bv.y;
        v.z = acc[r].z + bv.z;
        v.w = acc[r].w + bv.w;
        if (dorelu) {
          v.x = fmaxf(v.x, 0.f); v.y = fmaxf(v.y, 0.f);
          v.z = fmaxf(v.z, 0.f); v.w = fmaxf(v.w, 0.f);
        }
        if (zerorow0 && node == 0) { v.x = 0.f; v.y = 0.f; v.z = 0.f; v.w = 0.f; }
        *(h4*)&xouth[(size_t)node * 128 + f0] = f4h(v);
        if (writef32) *(float4*)&xout[(size_t)node * 128 + f0] = v;
      }
    }
  }
}

// Final MLP: 8 elems per 256-thread block (512 blocks). R14: x2 gathers in fp16.
__launch_bounds__(256, 4)
__global__ void final_kernel(const __half* __restrict__ x2h, const int* __restrict__ indices,
                             const float* __restrict__ Wc1t, const float* __restrict__ bc1,
                             const float* __restrict__ Wc2t, const float* __restrict__ bc2,
                             const float* __restrict__ Wc3, const float* __restrict__ bc3,
                             float* __restrict__ out) {
  __shared__ float ysm[FIN_EPB * 384];
  __shared__ float h1s[FIN_EPB * 128];
  __shared__ float h2s[FIN_EPB * 64];
  __shared__ int ind_s[FIN_EPB * 23];
  __shared__ float ccs[FIN_EPB];
  const int t = threadIdx.x;
  const int b0 = blockIdx.x * FIN_EPB;

  if (t < FIN_EPB * 23) ind_s[t] = indices[(size_t)b0 * 23 + t];
  __syncthreads();
  if (t < FIN_EPB) {
    int cc = 0;
#pragma unroll
    for (int j = 0; j < 20; ++j) cc += (ind_s[t * 23 + 3 + j] > 0) ? 1 : 0;
    ccs[t] = 1.0f / (float)(cc > 0 ? cc : 1);
  }
  __syncthreads();

  // ---- phase A ----
  {
#pragma unroll
    for (int q = 0; q < 2; ++q) {
      const int s = t + q * 256;
      const int e = s >> 6;
      const int hf = (s >> 5) & 1;
      const int fg = s & 31;
      const int idx = ind_s[e * 23 + hf];
      const h4 u = *(const h4*)&x2h[(size_t)idx * 128 + fg * 4];
      *(float4*)&ysm[e * 384 + hf * 128 + fg * 4] = h4f(u);
    }
    const int e = t >> 5;
    const int fg = t & 31;
    float4 acc = make_float4(0.f, 0.f, 0.f, 0.f);
#pragma unroll
    for (int j = 0; j < 20; ++j) {
      const int cj = ind_s[e * 23 + 3 + j];
      const h4 u = *(const h4*)&x2h[(size_t)cj * 128 + fg * 4];
      const float4 a = h4f(u);
      acc.x += a.x; acc.y += a.y; acc.z += a.z; acc.w += a.w;
    }
    const float sc = ccs[e];
    acc.x *= sc; acc.y *= sc; acc.z *= sc; acc.w *= sc;
    *(float4*)&ysm[e * 384 + 256 + fg * 4] = acc;
  }
  __syncthreads();

  // ---- phase B: layer 1 (384 -> 128), 4 elems per thread ----
  {
    const int f1 = t & 127;
    const int eh = t >> 7;
    float acc[4];
    const float b = bc1[f1];
#pragma unroll
    for (int i = 0; i < 4; ++i) acc[i] = b;
    for (int k = 0; k < 384; k += 4) {
      const float wv0 = Wc1t[(k + 0) * 128 + f1];
      const float wv1 = Wc1t[(k + 1) * 128 + f1];
      const float wv2 = Wc1t[(k + 2) * 128 + f1];
      const float wv3 = Wc1t[(k + 3) * 128 + f1];
#pragma unroll
      for (int i = 0; i < 4; ++i) {
        const float4 yv = *(const float4*)&ysm[(eh * 4 + i) * 384 + k];
        acc[i] += yv.x * wv0 + yv.y * wv1 + yv.z * wv2 + yv.w * wv3;
      }
    }
#pragma unroll
    for (int i = 0; i < 4; ++i)
      h1s[(eh * 4 + i) * 128 + f1] = fmaxf(acc[i], 0.f);
  }
  __syncthreads();

  // ---- phase C: layer 2 (128 -> 64), 2 elems per thread ----
  {
    const int f2 = t & 63;
    const int eg = t >> 6;
    float acc[2];
    const float b = bc2[f2];
#pragma unroll
    for (int i = 0; i < 2; ++i) acc[i] = b;
    for (int k = 0; k < 128; k += 4) {
      const float wv0 = Wc2t[(k + 0) * 64 + f2];
      const float wv1 = Wc2t[(k + 1) * 64 + f2];
      const float wv2 = Wc2t[(k + 2) * 64 + f2];
      const float wv3 = Wc2t[(k + 3) * 64 + f2];
#pragma unroll
      for (int i = 0; i < 2; ++i) {
        const float4 hv = *(const float4*)&h1s[(eg * 2 + i) * 128 + k];
        acc[i] += hv.x * wv0 + hv.y * wv1 + hv.z * wv2 + hv.w * wv3;
      }
    }
#pragma unroll
    for (int i = 0; i < 2; ++i)
      h2s[(eg * 2 + i) * 64 + f2] = fmaxf(acc[i], 0.f);
  }
  __syncthreads();

  // ---- phase D: layer 3 (64 -> 1), 32 lanes per element ----
  {
    const int e = t >> 5;
    const int l = t & 31;
    float p = h2s[e * 64 + l] * Wc3[l] + h2s[e * 64 + l + 32] * Wc3[l + 32];
#pragma unroll
    for (int o = 16; o > 0; o >>= 1) p += __shfl_down(p, o, 32);
    if (l == 0) out[b0 + e] = p + bc3[0];
  }
}

extern "C" void kernel_launch(void* const* d_in, const int* in_sizes, int n_in,
                              void* d_out, int out_size, void* d_ws, size_t ws_size,
                              hipStream_t stream) {
  const int* indices = (const int*)d_in[0];
  const int* src = (const int*)d_in[1];
  const int* dst = (const int*)d_in[2];
  const float* w = (const float*)d_in[3];
  const float* ndata = (const float*)d_in[4];
  const float* W1 = (const float*)d_in[5];
  const float* b1 = (const float*)d_in[6];
  const float* W2 = (const float*)d_in[7];
  const float* b2 = (const float*)d_in[8];
  const float* eps = (const float*)d_in[9];
  const float* Wc1 = (const float*)d_in[10];
  const float* bc1 = (const float*)d_in[11];
  const float* Wc2 = (const float*)d_in[12];
  const float* bc2 = (const float*)d_in[13];
  const float* Wc3 = (const float*)d_in[14];
  const float* bc3 = (const float*)d_in[15];
  float* out = (float*)d_out;

  const int E = in_sizes[1];
  const int N = in_sizes[4] / 128;
  const int B = in_sizes[0] / 23;

  char* ws = (char*)d_ws;
  size_t off = 0;
  auto alloc = [&](size_t bytes) -> char* {
    char* p = ws + off;
    off = (off + bytes + 255) & ~(size_t)255;
    return p;
  };
  const size_t Epad = (size_t)E + 8 * (size_t)N;   // worst-case padded edge count
  int* cnt = (int*)alloc((size_t)N * 4);
  int* prow = (int*)alloc((size_t)(N + 1) * 4);
  int* rank = (int*)alloc((size_t)E * 4);
  int* bsum = (int*)alloc(256 * 4);
  int2* epack = (int2*)alloc(Epad * 8);
  float* x1 = (float*)alloc((size_t)N * 128 * 4);          // f32 x1 (conv2 self term)
  __half* xh0 = (__half*)alloc((size_t)N * 128 * 2);       // fp16 ndata; reused as x2h
  __half* x1h = (__half*)alloc((size_t)N * 128 * 2);       // fp16 x1 (conv2 gathers)
  float* Wt1 = (float*)alloc(16384 * 4);
  float* Wt2 = (float*)alloc(16384 * 4);
  float* Wc1t = (float*)alloc(49152 * 4);
  float* Wc2t = (float*)alloc(8192 * 4);
  __half* x2h = xh0;   // xh0 dead after conv1; conv2 writes x2 (fp16) here

  const int ncast = (N * 128 + 7) / 8;                     // 1.6M cast threads
  int ninit = (N > 90112) ? N : 90112;
  if (ncast > ninit) ninit = ncast;
  init_kernel<<<(ninit + 255) / 256, 256, 0, stream>>>(W1, W2, Wc1, Wc2, ndata, xh0,
                                                       Wt1, Wt2, Wc1t, Wc2t, cnt, N);
  const int Eq = (E + 3) / 4;
  hist_kernel<<<(Eq + 255) / 256, 256, 0, stream>>>(dst, cnt, rank, E);
  const int nchunk = (N + 2047) / 2048;
  scan1_kernel<<<nchunk, 256, 0, stream>>>(cnt, prow, bsum, N);
  scan2_kernel<<<1, 64, 0, stream>>>(bsum, nchunk);
  const int nsc = (Eq > N) ? Eq : N;
  scatter_kernel<<<(nsc + 255) / 256, 256, 0, stream>>>(src, dst, w, prow, bsum, rank, cnt, epack, E, N);

  const int nconv = (N + CONV_NPB - 1) / CONV_NPB;
  // conv1: gathers fp16(ndata), self term f32 ndata; writes x1 (f32) + x1h (fp16)
  conv_kernel<<<nconv, 256, 0, stream>>>(ndata, xh0, x1, x1h, prow, bsum, cnt, epack,
                                         Wt1, b1, eps, 0, 1, 0, 1, N, nchunk);
  // conv2: gathers x1h, self term f32 x1; writes x2h (fp16 only, into xh0 buffer)
  conv_kernel<<<nconv, 256, 0, stream>>>(x1, x1h, nullptr, x2h, prow, bsum, cnt, epack,
                                         Wt2, b2, eps, 1, 0, 1, 0, N, nchunk);

  final_kernel<<<B / FIN_EPB, 256, 0, stream>>>(x2h, indices, Wc1t, bc1, Wc2t, bc2, Wc3, bc3, out);
}